// Round 2
// 9293.390 us; speedup vs baseline: 1.1611x; 1.1611x over previous
//
#include <hip/hip_runtime.h>

typedef unsigned short u16;
typedef unsigned int u32;
typedef __bf16 bf16x8 __attribute__((ext_vector_type(8)));
typedef float f32x4 __attribute__((ext_vector_type(4)));

static constexpr int S_ = 1024, D_ = 1024, H_ = 16, T_ = 1024, FF_ = 4096, L_ = 8, V_ = 32000, B_ = 2;
static constexpr int M_ = B_ * S_;   // 2048 token rows

#define DEV static __device__ __forceinline__

DEV u16 f2bf(float f){ u32 u = __float_as_uint(f); u += 0x7fffu + ((u >> 16) & 1u); return (u16)(u >> 16); }
DEV float bf2f(u16 h){ return __uint_as_float(((u32)h) << 16); }

// ---------------- fp32 -> bf16 convert (float4 / ushort4) ----------------
__global__ __launch_bounds__(256) void k_cvt(const float* __restrict__ src, u16* __restrict__ dst, long n4){
  long i = (long)blockIdx.x * 256 + threadIdx.x;
  if (i >= n4) return;
  float4 v = ((const float4*)src)[i];
  ushort4 o; o.x = f2bf(v.x); o.y = f2bf(v.y); o.z = f2bf(v.z); o.w = f2bf(v.w);
  ((ushort4*)dst)[i] = o;
}

// ---------------- embedding gather (fp32) ----------------
__global__ __launch_bounds__(256) void k_embed(const int* __restrict__ ids, const float* __restrict__ emb, float* __restrict__ x){
  int m = blockIdx.x;
  int id = ids[m];
  float4 v = ((const float4*)(emb + (size_t)id * D_))[threadIdx.x];
  ((float4*)(x + (size_t)m * D_))[threadIdx.x] = v;
}

// ---------------- layernorm fp32 -> bf16 (one block per row, D=1024) ----------------
__global__ __launch_bounds__(256) void k_ln(const float* __restrict__ x, const float* __restrict__ w,
                                            const float* __restrict__ b, u16* __restrict__ out){
  int row = blockIdx.x, t = threadIdx.x;
  float4 v = ((const float4*)(x + (size_t)row * D_))[t];
  float s = v.x + v.y + v.z + v.w;
  for (int off = 32; off; off >>= 1) s += __shfl_xor(s, off, 64);
  __shared__ float red[8];
  int wid = t >> 6, lane = t & 63;
  if (!lane) red[wid] = s;
  __syncthreads();
  float mu = (red[0] + red[1] + red[2] + red[3]) * (1.f / D_);
  float dx = v.x - mu, dy = v.y - mu, dz = v.z - mu, dw = v.w - mu;
  float s2 = dx*dx + dy*dy + dz*dz + dw*dw;
  for (int off = 32; off; off >>= 1) s2 += __shfl_xor(s2, off, 64);
  if (!lane) red[4 + wid] = s2;
  __syncthreads();
  float rs = rsqrtf((red[4] + red[5] + red[6] + red[7]) * (1.f / D_) + 1e-5f);
  float4 wv = ((const float4*)w)[t], bv = ((const float4*)b)[t];
  ushort4 o;
  o.x = f2bf(dx * rs * wv.x + bv.x);
  o.y = f2bf(dy * rs * wv.y + bv.y);
  o.z = f2bf(dz * rs * wv.z + bv.z);
  o.w = f2bf(dw * rs * wv.w + bv.w);
  ((ushort4*)(out + (size_t)row * D_))[t] = o;
}

// ---------------- RoPE + split to q,k,v (B,H,S,HD) bf16 ----------------
__global__ __launch_bounds__(256) void k_rope(const float* __restrict__ u, u16* __restrict__ qb,
                                              u16* __restrict__ kb, u16* __restrict__ vb){
  int m = blockIdx.x;               // b*S + s
  int b = m >> 10, s = m & (S_ - 1);
  const float* ur = u + (size_t)m * (3 * T_);
  for (int i = threadIdx.x; i < T_; i += 256){
    int h = i >> 6, d = i & 63, d2 = d & 31;
    float inv = expf(-(float)d2 * 0.28782313662425572f);   // ln(10000)/32
    float ang = (float)s * inv;
    float c, sn; sincosf(ang, &sn, &c);
    float qa = ur[i],      ka = ur[T_ + i];
    float qp = ur[i ^ 32], kp = ur[T_ + (i ^ 32)];
    float sgn = (d & 32) ? 1.f : -1.f;     // d<32: -q[d+32]; d>=32: +q[d-32]
    size_t o = ((size_t)(b * H_ + h) * S_ + s) * 64 + d;
    qb[o] = f2bf(qa * c + sgn * qp * sn);
    kb[o] = f2bf(ka * c + sgn * kp * sn);
    vb[o] = f2bf(ur[2 * T_ + i]);
  }
}

// ---------------- flash attention: 16 q-rows/block, k-tiles of 64, online softmax ----------------
// q in registers (float4 x16), K/V staged vectorized, all LDS traffic as b128.
// thread (row = t>>4, l16 = t&15); row-group is 16 contiguous lanes of ONE wave ->
// pr write/read needs no barrier. One k-slice per jj: ks = jj*16 + l16.
__global__ __launch_bounds__(256) void k_attn(const u16* __restrict__ qb, const u16* __restrict__ kb,
                                              const u16* __restrict__ vb, u16* __restrict__ out){
  __shared__ float kt[64][68];   // pad 68: b128 reads 16B-aligned, 2-way banks (free)
  __shared__ float vt[64][64];
  __shared__ float pr[16][68];
  int q0 = blockIdx.x * 16;
  int bh = blockIdx.y;
  int b = bh >> 4, hh = bh & 15;
  const u16* qp = qb + (size_t)bh * S_ * 64;
  const u16* kp = kb + (size_t)bh * S_ * 64;
  const u16* vp = vb + (size_t)bh * S_ * 64;
  int t = threadIdx.x;
  int row = t >> 4, l16 = t & 15;
  int qrow = q0 + row;
  // load this thread's q row into registers (16 lanes share the row; L1 broadcast)
  float4 qv[16];
  const ushort4* qr = (const ushort4*)(qp + (size_t)qrow * 64);
  #pragma unroll
  for (int d4 = 0; d4 < 16; ++d4){
    ushort4 u4 = qr[d4];
    qv[d4].x = bf2f(u4.x) * 0.125f;
    qv[d4].y = bf2f(u4.y) * 0.125f;
    qv[d4].z = bf2f(u4.z) * 0.125f;
    qv[d4].w = bf2f(u4.w) * 0.125f;
  }
  float m_i = -1e30f, l_i = 0.f;
  float o0 = 0.f, o1 = 0.f, o2 = 0.f, o3 = 0.f;
  int ktmax = q0 >> 6;
  for (int kti = 0; kti <= ktmax; ++kti){
    int k0 = kti << 6;
    __syncthreads();   // all waves done reading previous kt/vt
    for (int i = t; i < 64 * 16; i += 256){
      int r = i >> 4, d4 = i & 15;
      ushort4 kv = ((const ushort4*)(kp + (size_t)(k0 + r) * 64))[d4];
      ushort4 vv = ((const ushort4*)(vp + (size_t)(k0 + r) * 64))[d4];
      float4 kf, vf;
      kf.x = bf2f(kv.x); kf.y = bf2f(kv.y); kf.z = bf2f(kv.z); kf.w = bf2f(kv.w);
      vf.x = bf2f(vv.x); vf.y = bf2f(vv.y); vf.z = bf2f(vv.z); vf.w = bf2f(vv.w);
      *(float4*)&kt[r][d4 * 4] = kf;
      *(float4*)&vt[r][d4 * 4] = vf;
    }
    __syncthreads();
    // ---- scores: this thread owns ks = {l16, 16+l16, 32+l16, 48+l16} ----
    float sc0 = 0.f, sc1 = 0.f, sc2 = 0.f, sc3 = 0.f;
    #pragma unroll
    for (int d4 = 0; d4 < 16; ++d4){
      float4 q4 = qv[d4];
      float4 ka = *(const float4*)&kt[l16][d4 * 4];
      float4 kb4 = *(const float4*)&kt[16 + l16][d4 * 4];
      float4 kc = *(const float4*)&kt[32 + l16][d4 * 4];
      float4 kd = *(const float4*)&kt[48 + l16][d4 * 4];
      sc0 += q4.x*ka.x + q4.y*ka.y + q4.z*ka.z + q4.w*ka.w;
      sc1 += q4.x*kb4.x + q4.y*kb4.y + q4.z*kb4.z + q4.w*kb4.w;
      sc2 += q4.x*kc.x + q4.y*kc.y + q4.z*kc.z + q4.w*kc.w;
      sc3 += q4.x*kd.x + q4.y*kd.y + q4.z*kd.z + q4.w*kd.w;
    }
    sc0 = (k0 + l16      <= qrow) ? sc0 : -1e30f;
    sc1 = (k0 + 16 + l16 <= qrow) ? sc1 : -1e30f;
    sc2 = (k0 + 32 + l16 <= qrow) ? sc2 : -1e30f;
    sc3 = (k0 + 48 + l16 <= qrow) ? sc3 : -1e30f;
    float tm = fmaxf(fmaxf(sc0, sc1), fmaxf(sc2, sc3));
    for (int off = 8; off; off >>= 1) tm = fmaxf(tm, __shfl_xor(tm, off, 16));
    float nm = fmaxf(m_i, tm);
    float al = expf(m_i - nm);
    float p0 = expf(sc0 - nm), p1 = expf(sc1 - nm), p2 = expf(sc2 - nm), p3 = expf(sc3 - nm);
    float ps = p0 + p1 + p2 + p3;
    for (int off = 8; off; off >>= 1) ps += __shfl_xor(ps, off, 16);
    l_i = l_i * al + ps; m_i = nm;
    o0 *= al; o1 *= al; o2 *= al; o3 *= al;
    // pr sharing is intra-wave (row-group = 16 contiguous lanes) -> no barrier
    pr[row][l16]      = p0;
    pr[row][16 + l16] = p1;
    pr[row][32 + l16] = p2;
    pr[row][48 + l16] = p3;
    #pragma unroll
    for (int k4 = 0; k4 < 16; ++k4){
      float4 p4 = *(const float4*)&pr[row][k4 * 4];
      { float4 vv = *(const float4*)&vt[k4 * 4 + 0][l16 * 4]; o0 += p4.x*vv.x; o1 += p4.x*vv.y; o2 += p4.x*vv.z; o3 += p4.x*vv.w; }
      { float4 vv = *(const float4*)&vt[k4 * 4 + 1][l16 * 4]; o0 += p4.y*vv.x; o1 += p4.y*vv.y; o2 += p4.y*vv.z; o3 += p4.y*vv.w; }
      { float4 vv = *(const float4*)&vt[k4 * 4 + 2][l16 * 4]; o0 += p4.z*vv.x; o1 += p4.z*vv.y; o2 += p4.z*vv.z; o3 += p4.z*vv.w; }
      { float4 vv = *(const float4*)&vt[k4 * 4 + 3][l16 * 4]; o0 += p4.w*vv.x; o1 += p4.w*vv.y; o2 += p4.w*vv.z; o3 += p4.w*vv.w; }
    }
  }
  float il = 1.f / l_i;
  ushort4 ov; ov.x = f2bf(o0 * il); ov.y = f2bf(o1 * il); ov.z = f2bf(o2 * il); ov.w = f2bf(o3 * il);
  *(ushort4*)&out[(size_t)(b * S_ + qrow) * T_ + hh * 64 + l16 * 4] = ov;
}

// ---------------- bf16 NT GEMM: C[M,N] = A[M,K] * B[N,K]^T, 128x128 tile, 4 waves ----------------
// Grid: blockIdx.x = M-tile (FASTEST -> blocks sharing a B-panel are consecutive in
// dispatch order: B-panel becomes L2/LLC-resident instead of streaming from HBM).
// Register double-buffer: next K-step's global loads issued right after the barrier,
// consumed at the top of the next iteration (hides miss latency under MFMA).
// epi 0: C=acc (fp32).  epi 1: Cbf = bf16(gelu(acc+bias[n])).  epi 2: C = res + acc (+bias[n]).
__global__ __launch_bounds__(256) void k_gemm(const u16* __restrict__ A, const u16* __restrict__ B,
                                              int M, int N, int K,
                                              float* C, const float* __restrict__ bias,
                                              const float* res, u16* Cbf, int epi){
  __shared__ __align__(16) u16 la[128 * 40];   // pad 32->40: frag reads 2-way (free)
  __shared__ __align__(16) u16 lb[128 * 40];
  int t = threadIdx.x;
  int wave = t >> 6, lane = t & 63;
  int wm = (wave >> 1) << 6, wn = (wave & 1) << 6;   // 2x2 waves of 64x64
  int quad = lane >> 4, l16 = lane & 15;
  long mB = (long)blockIdx.x << 7;   // M-tile fastest
  long nB = (long)blockIdx.y << 7;
  int sr  = t >> 2;             // staging row 0..63
  int sc8 = (t & 3) << 3;       // staging col 0,8,16,24
  f32x4 acc[4][4];
  for (int i = 0; i < 4; ++i)
    for (int j = 0; j < 4; ++j)
      for (int r = 0; r < 4; ++r) acc[i][j][r] = 0.f;
  const u16* Ap0 = A + (mB + sr) * (long)K + sc8;
  const u16* Bp0 = B + (nB + sr) * (long)K + sc8;
  // prologue: first K-step into registers
  uint4 a0 = *(const uint4*)(Ap0);
  uint4 a1 = *(const uint4*)(Ap0 + (long)64 * K);
  uint4 b0 = *(const uint4*)(Bp0);
  uint4 b1 = *(const uint4*)(Bp0 + (long)64 * K);
  for (int k0 = 0; k0 < K; k0 += 32){
    *(uint4*)&la[sr * 40 + sc8] = a0;
    *(uint4*)&la[(sr + 64) * 40 + sc8] = a1;
    *(uint4*)&lb[sr * 40 + sc8] = b0;
    *(uint4*)&lb[(sr + 64) * 40 + sc8] = b1;
    __syncthreads();
    if (k0 + 32 < K){   // prefetch next K-step while MFMAs run
      a0 = *(const uint4*)(Ap0 + k0 + 32);
      a1 = *(const uint4*)(Ap0 + (long)64 * K + k0 + 32);
      b0 = *(const uint4*)(Bp0 + k0 + 32);
      b1 = *(const uint4*)(Bp0 + (long)64 * K + k0 + 32);
    }
    bf16x8 af[4], bfv[4];
    for (int i = 0; i < 4; ++i) af[i]  = *(const bf16x8*)&la[(wm + i * 16 + l16) * 40 + quad * 8];
    for (int j = 0; j < 4; ++j) bfv[j] = *(const bf16x8*)&lb[(wn + j * 16 + l16) * 40 + quad * 8];
    for (int i = 0; i < 4; ++i)
      for (int j = 0; j < 4; ++j)
        acc[i][j] = __builtin_amdgcn_mfma_f32_16x16x32_bf16(af[i], bfv[j], acc[i][j], 0, 0, 0);
    __syncthreads();
  }
  // C/D layout (verified m89/m91): col = lane&15, row = (lane>>4)*4 + reg
  for (int i = 0; i < 4; ++i){
    int gr = (int)mB + wm + i * 16 + quad * 4;
    for (int j = 0; j < 4; ++j){
      int gc = (int)nB + wn + j * 16 + l16;
      float bval = (bias && epi != 0) ? bias[gc] : 0.f;
      for (int r = 0; r < 4; ++r){
        long idx = (long)(gr + r) * N + gc;
        float v = acc[i][j][r];
        if (epi == 0){ C[idx] = v; }
        else if (epi == 1){ v += bval; Cbf[idx] = f2bf(0.5f * v * (1.f + erff(v * 0.70710678118f))); }
        else { v += res[idx] + bval; C[idx] = v; }
      }
    }
  }
}

extern "C" void kernel_launch(void* const* d_in, const int* in_sizes, int n_in,
                              void* d_out, int out_size, void* d_ws, size_t ws_size,
                              hipStream_t stream){
  const int*   ids = (const int*)  d_in[0];
  const float* emb = (const float*)d_in[1];
  const float* Wu  = (const float*)d_in[2];
  const float* Wo  = (const float*)d_in[3];
  const float* n1w = (const float*)d_in[4];
  const float* n1b = (const float*)d_in[5];
  const float* n2w = (const float*)d_in[6];
  const float* n2b = (const float*)d_in[7];
  const float* f1w = (const float*)d_in[8];
  const float* f1b = (const float*)d_in[9];
  const float* f2w = (const float*)d_in[10];
  const float* f2b = (const float*)d_in[11];
  const float* fnw = (const float*)d_in[12];
  const float* fnb = (const float*)d_in[13];

  char* p = (char*)d_ws;
  auto alloc = [&](size_t bytes) -> void* { void* r = p; p += (bytes + 255) & ~(size_t)255; return r; };
  u16*   wEmb = (u16*)  alloc((size_t)V_ * D_ * 2);      // 65.5 MB
  u16*   wWuL = (u16*)  alloc((size_t)3 * T_ * D_ * 2);  // per-layer bf16 weights (reused)
  u16*   wWoL = (u16*)  alloc((size_t)D_ * T_ * 2);
  u16*   wF1L = (u16*)  alloc((size_t)FF_ * D_ * 2);
  u16*   wF2L = (u16*)  alloc((size_t)D_ * FF_ * 2);
  float* x    = (float*)alloc((size_t)M_ * D_ * 4);
  float* u    = (float*)alloc((size_t)M_ * 3 * T_ * 4);
  u16*   actbf= (u16*)  alloc((size_t)M_ * D_ * 2);      // xn / attn-out / hin / xf (sequential lifetimes)
  u16*   qb   = (u16*)  alloc((size_t)M_ * T_ * 2);
  u16*   kb   = (u16*)  alloc((size_t)M_ * T_ * 2);
  u16*   vb   = (u16*)  alloc((size_t)M_ * T_ * 2);
  u16*   h    = (u16*)u;                                  // FF hidden bf16 aliases dead u (16.8MB <= 25.2MB)
  // total ws: ~134.5 MiB

  auto cvt = [&](const float* s, u16* d, long n){
    long n4 = n / 4;
    k_cvt<<<dim3((unsigned)((n4 + 255) / 256)), 256, 0, stream>>>(s, d, n4);
  };

  k_embed<<<M_, 256, 0, stream>>>(ids, emb, x);

  for (int i = 0; i < L_; ++i){
    cvt(Wu  + (size_t)i * 3 * T_ * D_, wWuL, (long)3 * T_ * D_);
    cvt(Wo  + (size_t)i * D_ * T_,     wWoL, (long)D_ * T_);
    cvt(f1w + (size_t)i * FF_ * D_,    wF1L, (long)FF_ * D_);
    cvt(f2w + (size_t)i * D_ * FF_,    wF2L, (long)D_ * FF_);

    k_ln<<<M_, 256, 0, stream>>>(x, n1w + i * D_, n1b + i * D_, actbf);
    k_gemm<<<dim3(M_ / 128, 3 * T_ / 128), 256, 0, stream>>>(actbf, wWuL, M_, 3 * T_, D_,
                                                             u, nullptr, nullptr, nullptr, 0);
    k_rope<<<M_, 256, 0, stream>>>(u, qb, kb, vb);
    k_attn<<<dim3(S_ / 16, B_ * H_), 256, 0, stream>>>(qb, kb, vb, actbf);
    k_gemm<<<dim3(M_ / 128, D_ / 128), 256, 0, stream>>>(actbf, wWoL, M_, D_, T_,
                                                         x, nullptr, x, nullptr, 2);
    k_ln<<<M_, 256, 0, stream>>>(x, n2w + i * D_, n2b + i * D_, actbf);
    k_gemm<<<dim3(M_ / 128, FF_ / 128), 256, 0, stream>>>(actbf, wF1L, M_, FF_, D_,
                                                          nullptr, f1b + (size_t)i * FF_, nullptr, h, 1);
    k_gemm<<<dim3(M_ / 128, D_ / 128), 256, 0, stream>>>(h, wF2L, M_, D_, FF_,
                                                         x, f2b + (size_t)i * D_, x, nullptr, 2);
  }

  cvt(emb, wEmb, (long)V_ * D_);
  k_ln<<<M_, 256, 0, stream>>>(x, fnw, fnb, actbf);
  k_gemm<<<dim3(M_ / 128, V_ / 128), 256, 0, stream>>>(actbf, wEmb, M_, V_, D_,
                                                       (float*)d_out, nullptr, nullptr, nullptr, 0);
}